// Round 10
// baseline (646.162 us; speedup 1.0000x reference)
//
#include <hip/hip_runtime.h>
#include <hip/hip_fp16.h>
#include <float.h>

#define DIMD   128
#define KCODES 1024
#define NROWS  65536
#define TAU    0.03f
#define SEG_R  16     // rows per segsum group
#define MEGAB  512    // mega-kernel blocks (512*4 waves = 2048 <= 8192 capacity: all co-resident)

typedef __attribute__((ext_vector_type(8)))  _Float16 half8;
typedef __attribute__((ext_vector_type(16))) float f32x16;

union U8 { uint4 u; half8 h; };

__device__ __forceinline__ unsigned packh2(float a, float b) {
    __half2 t = __floats2half2_rn(a, b);
    return *(unsigned*)&t;
}

// ---- fused: preconvert codebook f16-hi (blocks 0..63) + enorm (64..67) + zero flags (68) ----
__global__ __launch_bounds__(256) void pre_kernel(
    const float* __restrict__ embed, uint4* __restrict__ ehg,
    float* __restrict__ enorm, uint4* __restrict__ zero_region)
{
    if (blockIdx.x < 64) {
        int t = blockIdx.x * 256 + threadIdx.x;     // 0..16383
        int chunk = t >> 9;
        int s = (t >> 6) & 7;
        int L = t & 63;
        const float* src = embed + ((size_t)(chunk * 32 + (L & 31)) * DIMD) + s * 16 + (L >> 5) * 8;
        float4 a = *(const float4*)src;
        float4 b = *(const float4*)(src + 4);
        float f[8] = {a.x, a.y, a.z, a.w, b.x, b.y, b.z, b.w};
        uint4 H;
        unsigned* hw = (unsigned*)&H;
#pragma unroll
        for (int j = 0; j < 4; ++j) hw[j] = packh2(f[2 * j], f[2 * j + 1]);
        ehg[t] = H;
    } else if (blockIdx.x < 68) {
        int k = (blockIdx.x - 64) * 256 + threadIdx.x;
        const float4* e = (const float4*)(embed + (size_t)k * DIMD);
        float s = 0.f;
#pragma unroll
        for (int c = 0; c < DIMD / 4; ++c) {
            float4 v = e[c];
            s += v.x * v.x + v.y * v.y + v.z * v.z + v.w * v.w;
        }
        enorm[k] = s;
    } else {
        // zero counts (4KB) + wl_cnt/barrier page (4KB)
        uint4 z = {0, 0, 0, 0};
        zero_region[threadIdx.x] = z;
        zero_region[threadIdx.x + 256] = z;
    }
}

// ---------------- fused MFMA distance (f16 2-term: (xh+xl)·eh) + argmin (top-2) ----------------
// (256,2): VGPR cap 256 — kernel needs ~130. (256,3) capped at 84 -> 0.5GB spill (R8 regression).
__global__ __launch_bounds__(256, 2) void argmin_mfma(
    const float* __restrict__ x, const uint4* __restrict__ ehg,
    const float* __restrict__ enorm,
    int* __restrict__ ind_i, float* __restrict__ ind_f,
    int* __restrict__ wl, int* __restrict__ wl_cnt)
{
    __shared__ uint4 Bs[512];     // one chunk of eh f16 frags (8 KB)

    const int tid  = threadIdx.x;
    const int wave = tid >> 6;
    const int lane = tid & 63;
    const int n    = lane & 31;
    const int h    = lane >> 5;
    const int row0 = blockIdx.x * 128;
    const int rowA = row0 + wave * 32 + n;

    uint4 xh[8], xl[8];
    const float* xrow = x + (size_t)rowA * DIMD + h * 8;
#pragma unroll
    for (int s = 0; s < 8; ++s) {
        float4 a = *(const float4*)(xrow + s * 16);
        float4 b = *(const float4*)(xrow + s * 16 + 4);
        float f[8] = {a.x, a.y, a.z, a.w, b.x, b.y, b.z, b.w};
        unsigned* ph = (unsigned*)&xh[s];
        unsigned* pl = (unsigned*)&xl[s];
#pragma unroll
        for (int j = 0; j < 4; ++j) {
            float u0 = f[2 * j], u1 = f[2 * j + 1];
            __half2 hh = __floats2half2_rn(u0, u1);
            ph[j] = *(unsigned*)&hh;
            float2 back = __half22float2(hh);
            __half2 ll = __floats2half2_rn(u0 - back.x, u1 - back.y);
            pl[j] = *(unsigned*)&ll;
        }
    }

    float bestv[16], best2[16];
    int   besti[16];
#pragma unroll
    for (int r = 0; r < 16; ++r) { bestv[r] = FLT_MAX; best2[r] = FLT_MAX; besti[r] = 0; }

    for (int chunk = 0; chunk < KCODES / 32; ++chunk) {
        __syncthreads();
        {
            const uint4* sh = ehg + chunk * 512;
            Bs[tid]       = sh[tid];
            Bs[tid + 256] = sh[tid + 256];
        }
        float ee_val = enorm[chunk * 32 + n];
        __syncthreads();

        f32x16 acc;
#pragma unroll
        for (int r = 0; r < 16; ++r) acc[r] = 0.f;

#pragma unroll
        for (int s = 0; s < 8; ++s) {
            U8 ah, al, bh;
            ah.u = xh[s]; al.u = xl[s];
            bh.u = Bs[s * 64 + lane];
            acc = __builtin_amdgcn_mfma_f32_32x32x16_f16(ah.h, bh.h, acc, 0, 0, 0);
            acc = __builtin_amdgcn_mfma_f32_32x32x16_f16(al.h, bh.h, acc, 0, 0, 0);
        }

        const int nglob = chunk * 32 + n;
#pragma unroll
        for (int r = 0; r < 16; ++r) {
            float d = fmaf(-2.f, acc[r], ee_val);
            bool c1 = d < bestv[r];
            float t = c1 ? bestv[r] : d;
            best2[r] = fminf(best2[r], t);
            besti[r] = c1 ? nglob : besti[r];
            bestv[r] = fminf(bestv[r], d);
        }
    }

#pragma unroll
    for (int m = 1; m <= 16; m <<= 1) {
#pragma unroll
        for (int r = 0; r < 16; ++r) {
            float ov = __shfl_xor(bestv[r], m, 64);
            float o2 = __shfl_xor(best2[r], m, 64);
            int   oi = __shfl_xor(besti[r], m, 64);
            float hi = fmaxf(bestv[r], ov);
            best2[r] = fminf(fminf(best2[r], o2), hi);
            bool take = (ov < bestv[r]) || (ov == bestv[r] && oi < besti[r]);
            bestv[r] = take ? ov : bestv[r];
            besti[r] = take ? oi : besti[r];
        }
    }

    if (n == 0) {
#pragma unroll
        for (int r = 0; r < 16; ++r) {
            int row = row0 + wave * 32 + (r & 3) + 8 * (r >> 2) + 4 * h;
            ind_i[row] = besti[r];
            ind_f[row] = (float)besti[r];
            if (best2[r] - bestv[r] < TAU) {
                int p = atomicAdd(wl_cnt, 1);
                if (p < NROWS) wl[p] = row;
            }
        }
    }
}

// ---------------- device-scope grid barrier (all MEGAB blocks co-resident) ----------------
__device__ __forceinline__ void gsync(int* bar, int target) {
    __syncthreads();
    if (threadIdx.x == 0) {
        __threadfence();                      // release: publish this block's writes
        atomicAdd(bar, 1);                    // device-scope
        while (__hip_atomic_load(bar, __ATOMIC_ACQUIRE, __HIP_MEMORY_SCOPE_AGENT) < target) {
            __builtin_amdgcn_s_sleep(2);
        }
    }
    __syncthreads();
    __threadfence();                          // acquire: invalidate stale L1 for all waves
}

// ------- mega-kernel: recheck -> hist -> scan/cluster -> permbuild -> segsum -> embed -------
__global__ __launch_bounds__(256) void mega_kernel(
    const float* __restrict__ x, const float* __restrict__ embed,
    const float* __restrict__ cluster_size, const float* __restrict__ embed_avg,
    const float* __restrict__ enorm,
    int* __restrict__ ind_i, float* __restrict__ ind_f,
    const int* __restrict__ wl, const int* __restrict__ wl_cnt,
    int* __restrict__ counts, int* __restrict__ cursor, float* __restrict__ smoothed,
    int* __restrict__ perm, int* __restrict__ codes, float* __restrict__ embed_sum,
    float* __restrict__ out_q, float* __restrict__ out_cs,
    float* __restrict__ out_ea, float* __restrict__ out_en,
    int* __restrict__ bar)
{
    __shared__ float xs[DIMD];
    __shared__ float rv[256];
    __shared__ int   ri[256];
    __shared__ int   hcnt[KCODES];
    __shared__ int   hbase[KCODES];
    __shared__ int   ssum[256];
    __shared__ float tred[256];

    const int tid = threadIdx.x;
    const int bid = blockIdx.x;

    // ---- phase 1: exact fp32 re-check of near-tie rows ----
    {
        int count = *wl_cnt;
        if (count > NROWS) count = NROWS;
        for (int i = bid; i < count; i += MEGAB) {
            const int row = wl[i];
            __syncthreads();
            if (tid < DIMD) xs[tid] = x[(size_t)row * DIMD + tid];
            __syncthreads();
            const float4* xs4 = (const float4*)xs;
            float xn = 0.f;
#pragma unroll 8
            for (int c = 0; c < 32; ++c) {
                float4 v = xs4[c];
                xn += v.x * v.x + v.y * v.y + v.z * v.z + v.w * v.w;
            }
            float bv = FLT_MAX; int bi = 0;
#pragma unroll
            for (int c = 0; c < 4; ++c) {
                int code = tid * 4 + c;
                const float4* er = (const float4*)(embed + (size_t)code * DIMD);
                float acc = 0.f;
#pragma unroll 8
                for (int kk = 0; kk < 32; ++kk) {
                    float4 a = xs4[kk];
                    float4 b = er[kk];
                    acc += a.x * b.x + a.y * b.y + a.z * b.z + a.w * b.w;
                }
                float d = (xn - 2.0f * acc) + enorm[code];
                if (d < bv) { bv = d; bi = code; }
            }
            rv[tid] = bv; ri[tid] = bi;
            __syncthreads();
            for (int s = 128; s > 0; s >>= 1) {
                if (tid < s) {
                    if (rv[tid + s] < rv[tid] || (rv[tid + s] == rv[tid] && ri[tid + s] < ri[tid])) {
                        rv[tid] = rv[tid + s]; ri[tid] = ri[tid + s];
                    }
                }
                __syncthreads();
            }
            if (tid == 0) {
                int s_new = ri[0];
                if (s_new != ind_i[row]) {
                    ind_i[row] = s_new;
                    ind_f[row] = (float)s_new;
                }
            }
        }
    }
    gsync(bar, MEGAB * 1);

    // ---- phase 2: histogram (LDS-aggregated, 128 rows/block) ----
    {
#pragma unroll
        for (int i = 0; i < 4; ++i) hcnt[tid + 256 * i] = 0;
        __syncthreads();
        if (tid < 128) atomicAdd(&hcnt[ind_i[bid * 128 + tid]], 1);
        __syncthreads();
#pragma unroll
        for (int i = 0; i < 4; ++i) {
            int k = tid + 256 * i;
            int v = hcnt[k];
            if (v) atomicAdd(&counts[k], v);
        }
    }
    gsync(bar, MEGAB * 2);

    // ---- phase 3: exclusive scan + cluster EMA + smoothed (block 0 only) ----
    if (bid == 0) {
        int c[4];
#pragma unroll
        for (int j = 0; j < 4; ++j) c[j] = counts[4 * tid + j];
        int s0 = c[0], s1 = s0 + c[1], s2 = s1 + c[2], s3 = s2 + c[3];
        ssum[tid] = s3;
        __syncthreads();
        for (int d = 1; d < 256; d <<= 1) {
            int v = (tid >= d) ? ssum[tid - d] : 0;
            __syncthreads();
            ssum[tid] += v;
            __syncthreads();
        }
        int base = ssum[tid] - s3;
        cursor[4 * tid + 0] = base;
        cursor[4 * tid + 1] = base + s0;
        cursor[4 * tid + 2] = base + s1;
        cursor[4 * tid + 3] = base + s2;
        float cs[4], csum = 0.f;
#pragma unroll
        for (int j = 0; j < 4; ++j) {
            cs[j] = cluster_size[4 * tid + j] * 0.99f + (float)c[j] * 0.01f;
            out_cs[4 * tid + j] = cs[j];
            csum += cs[j];
        }
        tred[tid] = csum;
        __syncthreads();
        for (int s = 128; s > 0; s >>= 1) {
            if (tid < s) tred[tid] += tred[tid + s];
            __syncthreads();
        }
        float total = tred[0];
#pragma unroll
        for (int j = 0; j < 4; ++j)
            smoothed[4 * tid + j] = (cs[j] + 1e-6f) / (total + 1e-6f * (float)KCODES) * total;
    }
    gsync(bar, MEGAB * 3);

    // ---- phase 4: permutation build (two-level: LDS count -> 1 global atomic/code/block) ----
    {
        // zero embed_sum: 512 blocks x 64 uint4 = 512 KB
        if (tid < 64) {
            uint4 z = {0, 0, 0, 0};
            ((uint4*)embed_sum)[bid * 64 + tid] = z;
        }
#pragma unroll
        for (int i = 0; i < 4; ++i) hcnt[tid + 256 * i] = 0;
        __syncthreads();
        int row = bid * 128 + tid;   // 128 rows/block
        int k = -1;
        if (tid < 128) {
            k = ind_i[row];
            atomicAdd(&hcnt[k], 1);
        }
        __syncthreads();
#pragma unroll
        for (int i = 0; i < 4; ++i) {
            int kk = tid + 256 * i;
            int v = hcnt[kk];
            hbase[kk] = v ? atomicAdd(&cursor[kk], v) : 0;
        }
        __syncthreads();
        if (tid < 128) {
            int pos = atomicAdd(&hbase[k], 1);   // in-LDS ranking within block
            perm[pos] = row;
            codes[pos] = k;
        }
    }
    gsync(bar, MEGAB * 4);

    // ---- phase 5: balanced segmented sum + fused out_q gather ----
    {
        const int g = bid * 8 + (tid >> 5);     // 4096 groups of SEG_R rows
        const int c = tid & 31;
        const int base = g * SEG_R;
        float4 acc = {0.f, 0.f, 0.f, 0.f};
        int curk = codes[base];
#pragma unroll
        for (int j = 0; j < SEG_R; ++j) {
            int r = perm[base + j];
            int k = codes[base + j];
            float4 v = *(const float4*)(x + (size_t)r * DIMD + c * 4);
            float4 e = *(const float4*)(embed + (size_t)k * DIMD + c * 4);
            *(float4*)(out_q + (size_t)r * DIMD + c * 4) = e;
            if (k != curk) {
                float* dst = embed_sum + (size_t)curk * DIMD + c * 4;
                atomicAdd(dst + 0, acc.x);
                atomicAdd(dst + 1, acc.y);
                atomicAdd(dst + 2, acc.z);
                atomicAdd(dst + 3, acc.w);
                acc = v;
                curk = k;
            } else {
                acc.x += v.x; acc.y += v.y; acc.z += v.z; acc.w += v.w;
            }
        }
        float* dst = embed_sum + (size_t)curk * DIMD + c * 4;
        atomicAdd(dst + 0, acc.x);
        atomicAdd(dst + 1, acc.y);
        atomicAdd(dst + 2, acc.z);
        atomicAdd(dst + 3, acc.w);
    }
    gsync(bar, MEGAB * 5);

    // ---- phase 6: embed_avg EMA + embed_new (1 elem/thread: 512*256 = 131072) ----
    {
        int i = bid * 256 + tid;
        float ea = embed_avg[i] * 0.99f + embed_sum[i] * 0.01f;
        out_ea[i] = ea;
        out_en[i] = ea / smoothed[i >> 7];
    }
}

extern "C" void kernel_launch(void* const* d_in, const int* in_sizes, int n_in,
                              void* d_out, int out_size, void* d_ws, size_t ws_size,
                              hipStream_t stream) {
    const float* x            = (const float*)d_in[0];
    const float* embed        = (const float*)d_in[1];
    const float* cluster_size = (const float*)d_in[2];
    const float* embed_avg    = (const float*)d_in[3];

    float* out     = (float*)d_out;
    float* out_q   = out;                       // [65536*128]
    float* out_ind = out + 8388608;             // [65536]
    float* out_cs  = out + 8454144;             // [1024]
    float* out_ea  = out + 8455168;             // [1024*128]
    float* out_en  = out + 8586240;             // [1024*128]

    char* ws = (char*)d_ws;
    int*   ind_i     = (int*)(ws + 0);          // 256 KB
    float* enorm     = (float*)(ws + 262144);   // 4 KB
    int*   countsI   = (int*)(ws + 266240);     // 4 KB  \ zeroed by pre_kernel blk 68
    int*   wl_cnt    = (int*)(ws + 270336);     //       |
    int*   bar       = (int*)(ws + 270592);     // 4 KB  /  (same zeroed page as wl_cnt)
    int*   cursor    = (int*)(ws + 274432);     // 4 KB (fully written by scan phase)
    float* smoothed  = (float*)(ws + 278528);   // 4 KB
    int*   perm      = (int*)(ws + 286720);     // 256 KB
    int*   wl        = (int*)(ws + 548864);     // 256 KB (dead after mega phase 1)
    int*   codes     = (int*)(ws + 548864);     // 256 KB — ALIASES wl (phase-4+; barrier-separated)
    uint4* ehg       = (uint4*)(ws + 811008);   // 256 KB f16-hi codebook (dead after argmin)
    float* embed_sum = (float*)(ws + 811008);   // 512 KB — ALIASES ehg (zeroed in mega phase 4)

    pre_kernel<<<69, 256, 0, stream>>>(embed, ehg, enorm, (uint4*)countsI);
    argmin_mfma<<<NROWS / 128, 256, 0, stream>>>(
        x, ehg, enorm, ind_i, out_ind, wl, wl_cnt);
    mega_kernel<<<MEGAB, 256, 0, stream>>>(
        x, embed, cluster_size, embed_avg, enorm,
        ind_i, out_ind, wl, wl_cnt,
        countsI, cursor, smoothed,
        perm, codes, embed_sum,
        out_q, out_cs, out_ea, out_en, bar);
}